// Round 6
// baseline (1115.250 us; speedup 1.0000x reference)
//
#include <hip/hip_runtime.h>
#include <cstddef>
#include <cstdint>

#define B_    256
#define M_    21
#define L_    512
#define D_    256
#define T_    63
#define F_    32
#define NT_   16128   // B_*T_
#define HID_  512
#define KCP_  352     // M_*P_=336 padded to 32
#define H_    96
#define LAM_  0.01f
#define PZ_   16      // proj split-K z-blocks (BK=64: 16 k64-steps each, last z takes 12)

typedef __attribute__((ext_vector_type(8))) short short8;
typedef __attribute__((ext_vector_type(4))) float f32x4;
typedef unsigned int u32;
typedef const u32 __attribute__((address_space(1)))* gas1_t;
typedef u32 __attribute__((address_space(3)))* las3_t;

__device__ __forceinline__ void async_copy16(const void* g, void* l) {
  __builtin_amdgcn_global_load_lds((gas1_t)g, (las3_t)(uintptr_t)l, 16, 0, 0);
}
__device__ __forceinline__ unsigned short f2bf(float x) {   // RNE
  unsigned u = __float_as_uint(x);
  return (unsigned short)((u + 0x7FFF + ((u >> 16) & 1)) >> 16);
}
__device__ __forceinline__ float bf2f(unsigned short u) {
  return __uint_as_float(((unsigned)u) << 16);
}
__device__ __forceinline__ float gelu_exact(float v) {
  return 0.5f * v * (1.0f + erff(v * 0.70710678118654752f));
}
__device__ __forceinline__ float block_sum256(float v, float* red4) {
  #pragma unroll
  for (int off = 32; off > 0; off >>= 1) v += __shfl_down(v, off, 64);
  if ((threadIdx.x & 63) == 0) red4[threadIdx.x >> 6] = v;
  __syncthreads();
  float r = red4[0] + red4[1] + red4[2] + red4[3];
  __syncthreads();
  return r;
}
__device__ __forceinline__ float wave_sum(float v) {
  #pragma unroll
  for (int off = 1; off < 64; off <<= 1) v += __shfl_xor(v, off, 64);
  return v;
}

// ---------------------------------------------------------------- weight prep
struct CvtEnt { const float* src; unsigned short* dst; int rows, scol, dcol, blk0; };
struct CvtArgs { CvtEnt e[19]; int nent; };
__global__ __launch_bounds__(256) void wprep_kernel(CvtArgs a) {
  int blk = blockIdx.x, e = 0;
  while (e + 1 < a.nent && a.e[e + 1].blk0 <= blk) ++e;
  CvtEnt en = a.e[e];
  int idx = (blk - en.blk0) * 256 + threadIdx.x;
  int total = en.rows * en.dcol;
  if (idx >= total) return;
  int r = idx / en.dcol, c = idx - r * en.dcol;
  float v = (c < en.scol) ? en.src[(size_t)r * en.scol + c] : 0.f;
  en.dst[idx] = f2bf(v);
}

// interleaved cat weight: row 2c+p, col 2d+q
struct CatArgs { const float* wr[12]; const float* wi[12]; };
__global__ __launch_bounds__(256) void wcat_kernel(CatArgs a, unsigned short* dst) {
  int e = blockIdx.x >> 10;
  int idx = ((blockIdx.x & 1023) << 8) + threadIdx.x;
  int r = idx >> 9, c = idx & 511;
  int cp = r >> 1, p = r & 1, d = c >> 1, q = c & 1;
  const float* wr = a.wr[e];
  const float* wi = a.wi[e];
  float v;
  if (p == 0) v = (q == 0) ? wr[cp * 256 + d] : -wi[cp * 256 + d];
  else        v = (q == 0) ? wi[cp * 256 + d] :  wr[cp * 256 + d];
  dst[(size_t)e * 262144 + idx] = f2bf(v);
}

// ---------------------------------------------------------------- MFMA GEMM
// C = A @ W^T (+bias). Block tile (32*RT) x 128, 4 waves (2x2), each wave
// RT x 4 of 16x16x32-bf16 MFMA. BK = 32 or 64, LDS as [BK/32][rows][32] panels.
// RT=2: 64-row tile (24 KB LDS); RT=4: 128-row tile (32 KB LDS, 2x MFMA per
// barrier-drain phase -- m93's +51% lever for row-rich shapes).
// BIASM: 0 normal, 1 interleaved clin (odd col: 2*bi[col>>1]), 2 none+col guard.
// CVTA/CVTW: stage from fp32 with depth-1 register prefetch (loads for step
// ks+1 issued after barrier1, overlapped with MFMA of step ks).
template <int ACT, int OUTBF, int BIASM, int KSTEPS, int CVTA, int CVTW,
          int SHRINK, int MULPT, int SPLITK, int BK, int RT>
__global__ __launch_bounds__(256) void mm_kernel(
    const void* __restrict__ Av,
    const unsigned short* __restrict__ W0, const unsigned short* __restrict__ W1,
    const float* __restrict__ Wf,
    const float* __restrict__ b0, const float* __restrict__ b1,
    const unsigned short* __restrict__ ptb,
    void* __restrict__ Cv,
    const int K, const int Dout, const int ksteps_rt, const int yhalf,
    const int prow, const int totk) {
  constexpr int NP = BK / 32;
  constexpr int RWS = 32 * RT;
  __shared__ __align__(16) unsigned short As[NP * RWS * 32];
  __shared__ __align__(16) unsigned short Bs[NP * 128 * 32];
  const int tid = threadIdx.x, w = tid >> 6, lane = tid & 63;
  const int quad = lane >> 4, r16 = lane & 15;
  int nks = KSTEPS ? KSTEPS : ksteps_rt;
  const int ksbeg = SPLITK ? (int)blockIdx.z * nks : 0;
  if (SPLITK) { int rem = totk - ksbeg; if (nks > rem) nks = rem; }
  const int kst = ksbeg * BK;
  const int tower = ((int)blockIdx.y >= yhalf) ? 1 : 0;
  const unsigned short* Wb = tower ? W1 : W0;
  const float* bias = tower ? b1 : b0;

  const unsigned short* Ab = (const unsigned short*)Av;
  const float* Af = (const float*)Av;
  const unsigned short* gA = nullptr;
  unsigned short* lA = As + (w * 8 * RT) * 32;
  if (!CVTA) gA = Ab + (size_t)((int)blockIdx.y * RWS + w * 8 * RT + (lane >> 2)) * K
                     + kst + (lane & 3) * 8;
  const unsigned short* gB = nullptr;
  unsigned short* lB = Bs + (w * 32) * 32;
  if (!CVTW) gB = Wb + (size_t)((int)blockIdx.x * 128 + w * 32 + (lane >> 2)) * K
                     + kst + (lane & 3) * 8;
  // CVT mapping: 8 lanes per row (128B contiguous), rows crow+32*rr.
  const int crow = tid >> 3;            // 0..31
  const int ck4  = (tid & 7) << 2;      // 0,4,..,28

  float4 areg[NP][RT];
  float4 wreg[NP][4];
  auto loadA = [&](int ksi) {
    #pragma unroll
    for (int p = 0; p < NP; ++p)
      #pragma unroll
      for (int rr = 0; rr < RT; ++rr)
        areg[p][rr] = *reinterpret_cast<const float4*>(
            Af + (size_t)((int)blockIdx.y * RWS + crow + 32 * rr) * K
               + kst + ksi * BK + p * 32 + ck4);
  };
  auto loadW = [&](int ksi) {
    #pragma unroll
    for (int p = 0; p < NP; ++p)
      #pragma unroll
      for (int rr = 0; rr < 4; ++rr) {
        int wrow = (int)blockIdx.x * 128 + crow + 32 * rr;
        if (wrow >= Dout) wrow = Dout - 1;
        wreg[p][rr] = *reinterpret_cast<const float4*>(
            Wf + (size_t)wrow * K + kst + ksi * BK + p * 32 + ck4);
      }
  };
  if (CVTA) loadA(0);
  if (CVTW) loadW(0);

  f32x4 acc[RT][4];
  #pragma unroll
  for (int i = 0; i < RT; ++i)
    #pragma unroll
    for (int j = 0; j < 4; ++j)
      #pragma unroll
      for (int r = 0; r < 4; ++r) acc[i][j][r] = 0.f;

  for (int ks = 0; ks < nks; ++ks) {
    if (!CVTA) {
      #pragma unroll
      for (int p = 0; p < NP; ++p)
        #pragma unroll
        for (int c = 0; c < RT / 2; ++c)
          async_copy16(gA + (size_t)(c * 16) * K + p * 32,
                       lA + p * (RWS * 32) + c * 16 * 32);
      gA += BK;
    } else {
      #pragma unroll
      for (int p = 0; p < NP; ++p)
        #pragma unroll
        for (int rr = 0; rr < RT; ++rr) {
          float4 v = areg[p][rr];
          ushort4 o; o.x = f2bf(v.x); o.y = f2bf(v.y); o.z = f2bf(v.z); o.w = f2bf(v.w);
          *reinterpret_cast<ushort4*>(As + p * (RWS * 32) + (crow + 32 * rr) * 32 + ck4) = o;
        }
    }
    if (!CVTW) {
      #pragma unroll
      for (int p = 0; p < NP; ++p) {
        async_copy16(gB + p * 32, lB + p * 4096);
        async_copy16(gB + (size_t)16 * K + p * 32, lB + p * 4096 + 16 * 32);
      }
      gB += BK;
    } else {
      #pragma unroll
      for (int p = 0; p < NP; ++p)
        #pragma unroll
        for (int rr = 0; rr < 4; ++rr) {
          float4 v = wreg[p][rr];
          ushort4 o; o.x = f2bf(v.x); o.y = f2bf(v.y); o.z = f2bf(v.z); o.w = f2bf(v.w);
          *reinterpret_cast<ushort4*>(Bs + p * 4096 + (crow + 32 * rr) * 32 + ck4) = o;
        }
    }
    __syncthreads();
    if (CVTA && ks + 1 < nks) loadA(ks + 1);
    if (CVTW && ks + 1 < nks) loadW(ks + 1);
    #pragma unroll
    for (int p = 0; p < NP; ++p) {
      const unsigned short* pa = As + p * (RWS * 32) + ((w >> 1) * 16 * RT + r16) * 32 + quad * 8;
      const unsigned short* pb = Bs + p * 4096 + (64 * (w & 1) + r16) * 32 + quad * 8;
      short8 af[RT], bfv[4];
      #pragma unroll
      for (int i = 0; i < RT; ++i) af[i] = *reinterpret_cast<const short8*>(pa + i * 512);
      #pragma unroll
      for (int j = 0; j < 4; ++j) bfv[j] = *reinterpret_cast<const short8*>(pb + j * 512);
      #pragma unroll
      for (int i = 0; i < RT; ++i)
        #pragma unroll
        for (int j = 0; j < 4; ++j)
          acc[i][j] = __builtin_amdgcn_mfma_f32_16x16x32_bf16(af[i], bfv[j], acc[i][j], 0, 0, 0);
    }
    __syncthreads();
  }

  float* Cf = (float*)Cv;
  unsigned short* Cb = (unsigned short*)Cv;
  if (SPLITK) Cf += (size_t)blockIdx.z * prow * Dout;
  const int colb = (int)blockIdx.x * 128 + 64 * (w & 1) + r16;
  const int rowb = (int)blockIdx.y * RWS + 16 * RT * (w >> 1) + quad * 4;
  #pragma unroll
  for (int j = 0; j < 4; ++j) {
    int col = colb + 16 * j;
    float bv = 0.f;
    if (BIASM == 0) bv = bias[col];
    else if (BIASM == 1) bv = (col & 1) ? 2.0f * bias[col >> 1] : 0.f;
    bool colok = (BIASM != 2) || (col < Dout);
    #pragma unroll
    for (int i = 0; i < RT; ++i) {
      #pragma unroll
      for (int r = 0; r < 4; ++r) {
        int row = rowb + 16 * i + r;
        float v = acc[i][j][r] + bv;
        if (ACT == 1) v = gelu_exact(v);
        if (SHRINK) {
          float o = __shfl_xor(v, 1, 64);
          float mag = sqrtf(v * v + o * o);
          float s = (mag > LAM_) ? (mag - LAM_) / (mag + 1e-8f) : 0.f;
          v *= s;
        }
        if (MULPT) v *= bf2f(ptb[(size_t)row * Dout + col]);
        if (colok) {
          if (OUTBF) Cb[(size_t)row * Dout + col] = f2bf(v);
          else       Cf[(size_t)row * Dout + col] = v;
        }
      }
    }
  }
}

// ---------------------------------------------------------------- norm
__global__ __launch_bounds__(256) void norm_kernel(const float* __restrict__ x,
    float* __restrict__ xn, float* __restrict__ meanb, float* __restrict__ stdb) {
  __shared__ float red[4];
  int bm = blockIdx.x;
  const float* xr = x + (size_t)bm * L_;
  float v0 = xr[threadIdx.x], v1 = xr[threadIdx.x + 256];
  float mu = block_sum256(v0 + v1, red) * (1.0f / L_);
  float d0 = v0 - mu, d1 = v1 - mu;
  float sd = sqrtf(block_sum256(d0 * d0 + d1 * d1, red) * (1.0f / L_));
  float inv = 1.0f / (sd + 1e-5f);
  float* xo = xn + (size_t)bm * L_;
  xo[threadIdx.x] = d0 * inv;
  xo[threadIdx.x + 256] = d1 * inv;
  if (threadIdx.x == 0) { meanb[bm] = mu; stdb[bm] = sd; }
}

// ---------------------------------------------------------------- im2col -> bf16 K=352
__global__ __launch_bounds__(256) void im2col_kernel(const float* __restrict__ xn,
                                                     unsigned short* __restrict__ im) {
  int row = blockIdx.x;
  int b = row / T_, t = row - b * T_;
  const float* xb = xn + (size_t)b * M_ * L_ + t * 8;
  unsigned short* o = im + (size_t)row * KCP_;
  for (int i = threadIdx.x; i < KCP_; i += 256) {
    float v = 0.f;
    if (i < 336) { int m = i >> 4, p = i & 15; v = xb[m * L_ + p]; }
    o[i] = f2bf(v);
  }
}

// ---------------------------------------------------------------- pos-enc + dup into both towers
__global__ __launch_bounds__(256) void add_pe_kernel(const float* __restrict__ g0,
                                                     float* __restrict__ x32) {
  int row = blockIdx.x, d = threadIdx.x;
  int t = row % T_;
  size_t idx = (size_t)row * D_ + d;
  float freq = expf((float)(d & ~1) * (-9.210340371976184f / 256.0f));
  float ang = (float)t * freq;
  float pe = (d & 1) ? cosf(ang) : sinf(ang);
  float h = g0[idx] + pe;
  x32[idx] = h;
  x32[idx + (size_t)NT_ * D_] = h;
}

// ---------------------------------------------------------------- DFT along T (rfft)
__global__ __launch_bounds__(256) void dft_kernel(const float* __restrict__ X,
                                                  unsigned short* __restrict__ Zcat) {
  __shared__ float2 tw[T_ * F_];     // 15.75 KB
  int bt = blockIdx.x, d = threadIdx.x;
  for (int i = threadIdx.x; i < T_ * F_; i += 256) {
    int t = i >> 5, f = i & 31;
    int k = (f * t) % T_;
    float sn, cs;
    sincosf((6.283185307179586f / 63.0f) * (float)k, &sn, &cs);
    tw[i] = make_float2(cs, -sn);
  }
  __syncthreads();
  const float* xb = X + (size_t)bt * T_ * D_ + d;
  float ar[F_], ai[F_];
  #pragma unroll
  for (int f = 0; f < F_; ++f) { ar[f] = 0.f; ai[f] = 0.f; }
  for (int t = 0; t < T_; ++t) {
    float v = xb[(size_t)t * D_];
    const float2* w = &tw[t * F_];
    #pragma unroll
    for (int f = 0; f < F_; ++f) {
      float2 c = w[f];
      ar[f] = fmaf(v, c.x, ar[f]);
      ai[f] = fmaf(v, c.y, ai[f]);
    }
  }
  u32* z = reinterpret_cast<u32*>(Zcat + (size_t)bt * F_ * 512);
  #pragma unroll
  for (int f = 0; f < F_; ++f)
    z[f * 256 + d] = (u32)f2bf(ar[f]) | ((u32)f2bf(ai[f]) << 16);
}

// ---------------------------------------------------------------- irfft(n=63) -> pt bf16 (bf16 packed input)
__global__ __launch_bounds__(256) void irfft_kernel(const unsigned short* __restrict__ Y,
                                                    unsigned short* __restrict__ ptb) {
  __shared__ float2 tw[T_ * 31];     // 15.26 KB
  int bt = blockIdx.x, d = threadIdx.x;
  for (int i = threadIdx.x; i < T_ * 31; i += 256) {
    int t = i / 31, f = i - t * 31 + 1;
    int k = (f * t) % T_;
    float sn, cs;
    sincosf((6.283185307179586f / 63.0f) * (float)k, &sn, &cs);
    tw[i] = make_float2(cs * (2.0f / 63.0f), -sn * (2.0f / 63.0f));
  }
  __syncthreads();
  const unsigned short* yb = Y + (size_t)bt * F_ * 512 + 2 * d;
  float y0 = bf2f(yb[0]) * (1.0f / 63.0f);   // f=0: Re only
  float yr[31], yi[31];
  #pragma unroll
  for (int f = 1; f < F_; ++f) {
    u32 p = *reinterpret_cast<const u32*>(yb + (size_t)f * 512);
    yr[f - 1] = bf2f((unsigned short)(p & 0xffff));
    yi[f - 1] = bf2f((unsigned short)(p >> 16));
  }
  unsigned short* po = ptb + (size_t)bt * T_ * D_ + d;
  for (int t = 0; t < T_; ++t) {
    const float2* w = &tw[t * 31];
    float acc0 = y0, acc1 = 0.f;
    #pragma unroll
    for (int f = 0; f < 31; f += 2) {
      float2 c = w[f];
      acc0 = fmaf(yr[f], c.x, fmaf(yi[f], c.y, acc0));
      if (f + 1 < 31) {
        float2 c1 = w[f + 1];
        acc1 = fmaf(yr[f + 1], c1.x, fmaf(yi[f + 1], c1.y, acc1));
      }
    }
    po[(size_t)t * D_] = f2bf(acc0 + acc1);
  }
}

// ---------------------------------------------------------------- add + layernorm (wave per row)
__global__ __launch_bounds__(256) void ln_kernel(const float* __restrict__ outb,
    float* __restrict__ x, const float* __restrict__ g0, const float* __restrict__ b0,
    const float* __restrict__ g1, const float* __restrict__ b1, int yhalf) {
  int row = blockIdx.x * 4 + (threadIdx.x >> 6);
  int lane = threadIdx.x & 63;
  const float* g = (row >= yhalf) ? g1 : g0;
  const float* b = (row >= yhalf) ? b1 : b0;
  size_t base = (size_t)row * D_ + lane * 4;
  float4 ov = *reinterpret_cast<const float4*>(outb + base);
  float4 xv = *reinterpret_cast<const float4*>(x + base);
  float v0 = ov.x + xv.x, v1 = ov.y + xv.y, v2 = ov.z + xv.z, v3 = ov.w + xv.w;
  float mu = wave_sum(v0 + v1 + v2 + v3) * (1.0f / D_);
  v0 -= mu; v1 -= mu; v2 -= mu; v3 -= mu;
  float var = wave_sum(v0 * v0 + v1 * v1 + v2 * v2 + v3 * v3) * (1.0f / D_);
  float is = rsqrtf(var + 1e-5f);
  float4 gv = *reinterpret_cast<const float4*>(g + lane * 4);
  float4 bv = *reinterpret_cast<const float4*>(b + lane * 4);
  float4 o;
  o.x = v0 * is * gv.x + bv.x;
  o.y = v1 * is * gv.y + bv.y;
  o.z = v2 * is * gv.z + bv.z;
  o.w = v3 * is * gv.w + bv.w;
  *reinterpret_cast<float4*>(x + base) = o;
}

// ---------------------------------------------------------------- gate + blend -> bf16 feat (wave per row)
__global__ __launch_bounds__(256) void gate_feat_kernel(const float* __restrict__ x32,
    const float* __restrict__ gw, const float* __restrict__ gb,
    unsigned short* __restrict__ featbf) {
  int row = blockIdx.x * 4 + (threadIdx.x >> 6);
  int lane = threadIdx.x & 63;
  size_t base = (size_t)row * D_ + lane * 4;
  float4 tv = *reinterpret_cast<const float4*>(x32 + base);
  float4 sv = *reinterpret_cast<const float4*>(x32 + base + (size_t)NT_ * D_);
  float4 gv = *reinterpret_cast<const float4*>(gw + lane * 4);
  float dot = wave_sum(tv.x * gv.x + tv.y * gv.y + tv.z * gv.z + tv.w * gv.w) + gb[0];
  float gate = 1.0f / (1.0f + expf(-dot));
  ushort4 o;
  o.x = f2bf(gate * tv.x + (1.0f - gate) * sv.x);
  o.y = f2bf(gate * tv.y + (1.0f - gate) * sv.y);
  o.z = f2bf(gate * tv.z + (1.0f - gate) * sv.z);
  o.w = f2bf(gate * tv.w + (1.0f - gate) * sv.w);
  *reinterpret_cast<ushort4*>(featbf + base) = o;
}

// ---------------------------------------------------------------- split-K reduce + bias + rescale
__global__ __launch_bounds__(256) void final_kernel(const float* __restrict__ part,
    const float* __restrict__ pb, const float* __restrict__ stdb,
    const float* __restrict__ meanb, float* __restrict__ y) {
  int i = blockIdx.x * 256 + threadIdx.x;         // 516096
  float acc = 0.f;
  #pragma unroll
  for (int z = 0; z < PZ_; ++z) acc += part[(size_t)z * 516096 + i];
  int b = i / 2016;
  int col = i - b * 2016;
  int m = col / H_;
  float sc = stdb[b * M_ + m] + 1e-5f;
  y[i] = (acc + pb[col]) * sc + meanb[b * M_ + m];
}

// ---------------------------------------------------------------- launch
extern "C" void kernel_launch(void* const* d_in, const int* in_sizes, int n_in,
                              void* d_out, int out_size, void* d_ws, size_t ws_size,
                              hipStream_t stream) {
  const float* x      = (const float*)d_in[0];
  const float* conv_w = (const float*)d_in[1];
  const float* conv_b = (const float*)d_in[2];
  const float* tP[16];
  const float* sP[16];
  for (int i = 0; i < 16; ++i) tP[i] = (const float*)d_in[3 + i];
  for (int i = 0; i < 16; ++i) sP[i] = (const float*)d_in[19 + i];
  const float* gate_w = (const float*)d_in[35];
  const float* gate_b = (const float*)d_in[36];
  const float* proj_w = (const float*)d_in[37];
  const float* proj_b = (const float*)d_in[38];
  float* out = (float*)d_out;

  // ---- workspace (floats): total 27,646,480 f = 110.6 MB
  float* ws    = (float*)d_ws;
  float* x32   = ws;                               // 8,257,536 (2 towers x NT x D)
  unsigned short* wb = (unsigned short*)(x32 + 8257536);  // 5,201,920 shorts
  float* meanb = x32 + 8257536 + 2600960;          // 5,376
  float* stdb  = meanb + 5376;                     // 5,376
  float* R1    = stdb + 5376 + 16;                 // 8,388,608
  float* R2    = R1 + 8388608;                     // 8,388,608

  unsigned short* im2colB = (unsigned short*)R1;             // pre-loop
  unsigned short* Zcat    = (unsigned short*)R1;             // dft -> H1
  unsigned short* Ycat1   = (unsigned short*)(R1 + 4194304); // H1 -> H2
  unsigned short* ptb     = (unsigned short*)(R1 + 4194304); // irfft -> Gp
  unsigned short* gp      = (unsigned short*)R1;             // Gp -> Tw
  unsigned short* featbf  = (unsigned short*)R1;             // post-loop

  float* xn     = R2;                              // pre-loop
  float* g0buf  = R2;                              // conv out (pre-loop)
  unsigned short* Ycat2b = (unsigned short*)R2;    // H2 -> irfft (bf16 packed)
  unsigned short* hidB = (unsigned short*)R2;      // Ge -> Gp
  float* outb   = R2;                              // Tw -> ln
  float* part   = R2;                              // proj partials (16 x 516096 = 8.26M f)

  unsigned short* convW = wb;                      // 256*352
  unsigned short* sets  = wb + 90112;              // 6 * (Gew 131072 + Gpw 131072 + Tw 65536)
  unsigned short* catW  = wb + 90112 + 1966080;    // 12 * 262144

  // ---- weight prep
  CvtArgs ca; int blk0 = 0, ne = 0;
  auto add_ent = [&](const float* s, unsigned short* d, int rows, int scol, int dcol) {
    ca.e[ne].src = s; ca.e[ne].dst = d; ca.e[ne].rows = rows;
    ca.e[ne].scol = scol; ca.e[ne].dcol = dcol; ca.e[ne].blk0 = blk0;
    blk0 += (rows * dcol + 255) / 256; ++ne;
  };
  add_ent(conv_w, convW, 256, 336, 352);
  for (int tw = 0; tw < 2; ++tw) {
    const float** Pp = tw ? (const float**)sP : (const float**)tP;
    for (int l = 0; l < 3; ++l) {
      unsigned short* sb = sets + (size_t)(tw * 3 + l) * 327680;
      add_ent(Pp[2] + (size_t)l * 131072, sb,          512, 256, 256);  // Gew
      add_ent(Pp[4] + (size_t)l * 131072, sb + 131072, 256, 512, 512);  // Gpw
      add_ent(Pp[0] + (size_t)l * 65536,  sb + 262144, 256, 256, 256);  // Tw
    }
  }
  ca.nent = ne;
  wprep_kernel<<<blk0, 256, 0, stream>>>(ca);

  CatArgs cat;
  for (int tw = 0; tw < 2; ++tw) {
    const float** Pp = tw ? (const float**)sP : (const float**)tP;
    for (int l = 0; l < 3; ++l) {
      int e0 = (tw * 3 + l) * 2;
      cat.wr[e0]     = Pp[6]  + (size_t)l * 65536;   // H1Wr
      cat.wi[e0]     = Pp[7]  + (size_t)l * 65536;   // H1Wi
      cat.wr[e0 + 1] = Pp[10] + (size_t)l * 65536;   // H2Wr
      cat.wi[e0 + 1] = Pp[11] + (size_t)l * 65536;   // H2Wi
    }
  }
  wcat_kernel<<<12 * 1024, 256, 0, stream>>>(cat, catW);

  // ---- stem
  norm_kernel<<<B_ * M_, 256, 0, stream>>>(x, xn, meanb, stdb);
  im2col_kernel<<<NT_, 256, 0, stream>>>(xn, im2colB);
  mm_kernel<0, 0, 0, 11, 0, 0, 0, 0, 0, 32, 2><<<dim3(2, 252), 256, 0, stream>>>(
      im2colB, convW, convW, nullptr, conv_b, conv_b, nullptr, g0buf,
      KCP_, 256, 0, 1 << 30, 0, 0);
  add_pe_kernel<<<NT_, 256, 0, stream>>>(g0buf, x32);

  // ---- layers (both towers batched; freq branch first, then MLP with x pt fuse)
  // Ge/Gp/Tw use RT=4 (128-row tiles, y=252 = 2 towers x 126): 2x MFMA per
  // barrier phase, half the drain events (m93 lever). H1/H2 stay RT=2 (rows
  // 16384 -> y=128 would drop below co-residency).
  for (int l = 0; l < 3; ++l) {
    unsigned short* st0 = sets + (size_t)l * 327680;
    unsigned short* st1 = sets + (size_t)(3 + l) * 327680;
    unsigned short* c1t0 = catW + (size_t)((0 + l) * 2) * 262144;
    unsigned short* c2t0 = c1t0 + 262144;
    unsigned short* c1t1 = catW + (size_t)((3 + l) * 2) * 262144;
    unsigned short* c2t1 = c1t1 + 262144;

    dft_kernel<<<2 * B_, 256, 0, stream>>>(x32, Zcat);
    mm_kernel<0, 1, 1, 8, 0, 0, 1, 0, 0, 64, 2><<<dim3(4, 256), 256, 0, stream>>>(
        Zcat, c1t0, c1t1, nullptr, tP[9] + (size_t)l * D_, sP[9] + (size_t)l * D_,
        nullptr, Ycat1, 512, 512, 0, 128, 0, 0);
    mm_kernel<0, 1, 1, 8, 0, 0, 0, 0, 0, 64, 2><<<dim3(4, 256), 256, 0, stream>>>(
        Ycat1, c2t0, c2t1, nullptr, tP[13] + (size_t)l * D_, sP[13] + (size_t)l * D_,
        nullptr, Ycat2b, 512, 512, 0, 128, 0, 0);
    irfft_kernel<<<2 * B_, 256, 0, stream>>>(Ycat2b, ptb);
    mm_kernel<1, 1, 0, 4, 1, 0, 0, 0, 0, 64, 4><<<dim3(4, 252), 256, 0, stream>>>(
        x32, st0, st1, nullptr, tP[3] + (size_t)l * HID_, sP[3] + (size_t)l * HID_,
        nullptr, hidB, 256, 512, 0, 126, 0, 0);
    mm_kernel<0, 1, 0, 8, 0, 0, 0, 1, 0, 64, 4><<<dim3(2, 252), 256, 0, stream>>>(
        hidB, st0 + 131072, st1 + 131072, nullptr,
        tP[5] + (size_t)l * D_, sP[5] + (size_t)l * D_, ptb, gp, 512, 256, 0, 126, 0, 0);
    mm_kernel<0, 0, 0, 4, 0, 0, 0, 0, 0, 64, 4><<<dim3(2, 252), 256, 0, stream>>>(
        gp, st0 + 262144, st1 + 262144, nullptr,
        tP[1] + (size_t)l * D_, sP[1] + (size_t)l * D_, nullptr, outb, 256, 256, 0, 126, 0, 0);
    ln_kernel<<<2 * NT_ / 4, 256, 0, stream>>>(outb, x32,
        tP[14] + (size_t)l * D_, tP[15] + (size_t)l * D_,
        sP[14] + (size_t)l * D_, sP[15] + (size_t)l * D_, NT_);
  }

  // ---- head
  gate_feat_kernel<<<NT_ / 4, 256, 0, stream>>>(x32, gate_w, gate_b, featbf);
  // proj: BK=64, A async bf16 + W fp32 reg-staged, PZ=16 z-blocks of 16
  // k64-steps (last z takes 12; totk=252 in BK units). R2 known-best config.
  mm_kernel<0, 0, 2, 0, 0, 1, 0, 0, 1, 64, 2><<<dim3(16, 4, PZ_), 256, 0, stream>>>(
      featbf, nullptr, nullptr, proj_w, nullptr, nullptr, nullptr, part,
      NT_, 2016, 16, 1 << 30, 256, 252);
  final_kernel<<<2016, 256, 0, stream>>>(part, proj_b, stdb, meanb, out);
}

// Round 7
// 984.018 us; speedup vs baseline: 1.1334x; 1.1334x over previous
//
#include <hip/hip_runtime.h>
#include <cstddef>
#include <cstdint>

#define B_    256
#define M_    21
#define L_    512
#define D_    256
#define T_    63
#define F_    32
#define NT_   16128   // B_*T_
#define HID_  512
#define KCP_  352     // M_*P_=336 padded to 32
#define H_    96
#define LAM_  0.01f
#define PZ_   16      // proj split-K z-blocks (BK=64: 16 k64-steps each, last z takes 12)

typedef __attribute__((ext_vector_type(8))) short short8;
typedef __attribute__((ext_vector_type(4))) float f32x4;
typedef unsigned int u32;
typedef const u32 __attribute__((address_space(1)))* gas1_t;
typedef u32 __attribute__((address_space(3)))* las3_t;

__device__ __forceinline__ void async_copy16(const void* g, void* l) {
  __builtin_amdgcn_global_load_lds((gas1_t)g, (las3_t)(uintptr_t)l, 16, 0, 0);
}
__device__ __forceinline__ unsigned short f2bf(float x) {   // RNE
  unsigned u = __float_as_uint(x);
  return (unsigned short)((u + 0x7FFF + ((u >> 16) & 1)) >> 16);
}
__device__ __forceinline__ float bf2f(unsigned short u) {
  return __uint_as_float(((unsigned)u) << 16);
}
__device__ __forceinline__ float gelu_exact(float v) {
  return 0.5f * v * (1.0f + erff(v * 0.70710678118654752f));
}
__device__ __forceinline__ float block_sum256(float v, float* red4) {
  #pragma unroll
  for (int off = 32; off > 0; off >>= 1) v += __shfl_down(v, off, 64);
  if ((threadIdx.x & 63) == 0) red4[threadIdx.x >> 6] = v;
  __syncthreads();
  float r = red4[0] + red4[1] + red4[2] + red4[3];
  __syncthreads();
  return r;
}
__device__ __forceinline__ float wave_sum(float v) {
  #pragma unroll
  for (int off = 1; off < 64; off <<= 1) v += __shfl_xor(v, off, 64);
  return v;
}

// ---------------------------------------------------------------- weight prep
struct CvtEnt { const float* src; unsigned short* dst; int rows, scol, dcol, blk0; };
struct CvtArgs { CvtEnt e[19]; int nent; };
__global__ __launch_bounds__(256) void wprep_kernel(CvtArgs a) {
  int blk = blockIdx.x, e = 0;
  while (e + 1 < a.nent && a.e[e + 1].blk0 <= blk) ++e;
  CvtEnt en = a.e[e];
  int idx = (blk - en.blk0) * 256 + threadIdx.x;
  int total = en.rows * en.dcol;
  if (idx >= total) return;
  int r = idx / en.dcol, c = idx - r * en.dcol;
  float v = (c < en.scol) ? en.src[(size_t)r * en.scol + c] : 0.f;
  en.dst[idx] = f2bf(v);
}

// interleaved cat weight: row 2c+p, col 2d+q
struct CatArgs { const float* wr[12]; const float* wi[12]; };
__global__ __launch_bounds__(256) void wcat_kernel(CatArgs a, unsigned short* dst) {
  int e = blockIdx.x >> 10;
  int idx = ((blockIdx.x & 1023) << 8) + threadIdx.x;
  int r = idx >> 9, c = idx & 511;
  int cp = r >> 1, p = r & 1, d = c >> 1, q = c & 1;
  const float* wr = a.wr[e];
  const float* wi = a.wi[e];
  float v;
  if (p == 0) v = (q == 0) ? wr[cp * 256 + d] : -wi[cp * 256 + d];
  else        v = (q == 0) ? wi[cp * 256 + d] :  wr[cp * 256 + d];
  dst[(size_t)e * 262144 + idx] = f2bf(v);
}

// ---------------------------------------------------------------- MFMA GEMM
// C = A @ W^T (+bias). Block tile (32*RT) x 128, 4 waves (2x2), each wave
// RT x 4 of 16x16x32-bf16 MFMA. BK = 32 or 64, LDS as [BK/32][rows][32] panels.
// BIASM: 0 normal, 1 interleaved clin (odd col: 2*bi[col>>1]), 2 none+col guard.
// CVTA/CVTW: stage from fp32 with depth-1 register prefetch.
// PEW: conv stem epilogue -- add positional encoding, dual-write both towers.
template <int ACT, int OUTBF, int BIASM, int KSTEPS, int CVTA, int CVTW,
          int SHRINK, int MULPT, int SPLITK, int BK, int RT, int PEW>
__global__ __launch_bounds__(256) void mm_kernel(
    const void* __restrict__ Av,
    const unsigned short* __restrict__ W0, const unsigned short* __restrict__ W1,
    const float* __restrict__ Wf,
    const float* __restrict__ b0, const float* __restrict__ b1,
    const unsigned short* __restrict__ ptb,
    void* __restrict__ Cv,
    const int K, const int Dout, const int ksteps_rt, const int yhalf,
    const int prow, const int totk) {
  constexpr int NP = BK / 32;
  constexpr int RWS = 32 * RT;
  __shared__ __align__(16) unsigned short As[NP * RWS * 32];
  __shared__ __align__(16) unsigned short Bs[NP * 128 * 32];
  const int tid = threadIdx.x, w = tid >> 6, lane = tid & 63;
  const int quad = lane >> 4, r16 = lane & 15;
  int nks = KSTEPS ? KSTEPS : ksteps_rt;
  const int ksbeg = SPLITK ? (int)blockIdx.z * nks : 0;
  if (SPLITK) { int rem = totk - ksbeg; if (nks > rem) nks = rem; }
  const int kst = ksbeg * BK;
  const int tower = ((int)blockIdx.y >= yhalf) ? 1 : 0;
  const unsigned short* Wb = tower ? W1 : W0;
  const float* bias = tower ? b1 : b0;

  const unsigned short* Ab = (const unsigned short*)Av;
  const float* Af = (const float*)Av;
  const unsigned short* gA = nullptr;
  unsigned short* lA = As + (w * 8 * RT) * 32;
  if (!CVTA) gA = Ab + (size_t)((int)blockIdx.y * RWS + w * 8 * RT + (lane >> 2)) * K
                     + kst + (lane & 3) * 8;
  const unsigned short* gB = nullptr;
  unsigned short* lB = Bs + (w * 32) * 32;
  if (!CVTW) gB = Wb + (size_t)((int)blockIdx.x * 128 + w * 32 + (lane >> 2)) * K
                     + kst + (lane & 3) * 8;
  // CVT mapping: 8 lanes per row (128B contiguous), rows crow+32*rr.
  const int crow = tid >> 3;            // 0..31
  const int ck4  = (tid & 7) << 2;      // 0,4,..,28

  float4 areg[NP][RT];
  float4 wreg[NP][4];
  auto loadA = [&](int ksi) {
    #pragma unroll
    for (int p = 0; p < NP; ++p)
      #pragma unroll
      for (int rr = 0; rr < RT; ++rr)
        areg[p][rr] = *reinterpret_cast<const float4*>(
            Af + (size_t)((int)blockIdx.y * RWS + crow + 32 * rr) * K
               + kst + ksi * BK + p * 32 + ck4);
  };
  auto loadW = [&](int ksi) {
    #pragma unroll
    for (int p = 0; p < NP; ++p)
      #pragma unroll
      for (int rr = 0; rr < 4; ++rr) {
        int wrow = (int)blockIdx.x * 128 + crow + 32 * rr;
        if (wrow >= Dout) wrow = Dout - 1;
        wreg[p][rr] = *reinterpret_cast<const float4*>(
            Wf + (size_t)wrow * K + kst + ksi * BK + p * 32 + ck4);
      }
  };
  if (CVTA) loadA(0);
  if (CVTW) loadW(0);

  f32x4 acc[RT][4];
  #pragma unroll
  for (int i = 0; i < RT; ++i)
    #pragma unroll
    for (int j = 0; j < 4; ++j)
      #pragma unroll
      for (int r = 0; r < 4; ++r) acc[i][j][r] = 0.f;

  for (int ks = 0; ks < nks; ++ks) {
    if (!CVTA) {
      #pragma unroll
      for (int p = 0; p < NP; ++p)
        #pragma unroll
        for (int c = 0; c < RT / 2; ++c)
          async_copy16(gA + (size_t)(c * 16) * K + p * 32,
                       lA + p * (RWS * 32) + c * 16 * 32);
      gA += BK;
    } else {
      #pragma unroll
      for (int p = 0; p < NP; ++p)
        #pragma unroll
        for (int rr = 0; rr < RT; ++rr) {
          float4 v = areg[p][rr];
          ushort4 o; o.x = f2bf(v.x); o.y = f2bf(v.y); o.z = f2bf(v.z); o.w = f2bf(v.w);
          *reinterpret_cast<ushort4*>(As + p * (RWS * 32) + (crow + 32 * rr) * 32 + ck4) = o;
        }
    }
    if (!CVTW) {
      #pragma unroll
      for (int p = 0; p < NP; ++p) {
        async_copy16(gB + p * 32, lB + p * 4096);
        async_copy16(gB + (size_t)16 * K + p * 32, lB + p * 4096 + 16 * 32);
      }
      gB += BK;
    } else {
      #pragma unroll
      for (int p = 0; p < NP; ++p)
        #pragma unroll
        for (int rr = 0; rr < 4; ++rr) {
          float4 v = wreg[p][rr];
          ushort4 o; o.x = f2bf(v.x); o.y = f2bf(v.y); o.z = f2bf(v.z); o.w = f2bf(v.w);
          *reinterpret_cast<ushort4*>(Bs + p * 4096 + (crow + 32 * rr) * 32 + ck4) = o;
        }
    }
    __syncthreads();
    if (CVTA && ks + 1 < nks) loadA(ks + 1);
    if (CVTW && ks + 1 < nks) loadW(ks + 1);
    #pragma unroll
    for (int p = 0; p < NP; ++p) {
      const unsigned short* pa = As + p * (RWS * 32) + ((w >> 1) * 16 * RT + r16) * 32 + quad * 8;
      const unsigned short* pb = Bs + p * 4096 + (64 * (w & 1) + r16) * 32 + quad * 8;
      short8 af[RT], bfv[4];
      #pragma unroll
      for (int i = 0; i < RT; ++i) af[i] = *reinterpret_cast<const short8*>(pa + i * 512);
      #pragma unroll
      for (int j = 0; j < 4; ++j) bfv[j] = *reinterpret_cast<const short8*>(pb + j * 512);
      #pragma unroll
      for (int i = 0; i < RT; ++i)
        #pragma unroll
        for (int j = 0; j < 4; ++j)
          acc[i][j] = __builtin_amdgcn_mfma_f32_16x16x32_bf16(af[i], bfv[j], acc[i][j], 0, 0, 0);
    }
    __syncthreads();
  }

  float* Cf = (float*)Cv;
  unsigned short* Cb = (unsigned short*)Cv;
  if (SPLITK) Cf += (size_t)blockIdx.z * prow * Dout;
  const int colb = (int)blockIdx.x * 128 + 64 * (w & 1) + r16;
  const int rowb = (int)blockIdx.y * RWS + 16 * RT * (w >> 1) + quad * 4;
  #pragma unroll
  for (int j = 0; j < 4; ++j) {
    int col = colb + 16 * j;
    float bv = 0.f;
    if (BIASM == 0) bv = bias[col];
    else if (BIASM == 1) bv = (col & 1) ? 2.0f * bias[col >> 1] : 0.f;
    bool colok = (BIASM != 2) || (col < Dout);
    #pragma unroll
    for (int i = 0; i < RT; ++i) {
      #pragma unroll
      for (int r = 0; r < 4; ++r) {
        int row = rowb + 16 * i + r;
        float v = acc[i][j][r] + bv;
        if (ACT == 1) v = gelu_exact(v);
        if (SHRINK) {
          float o = __shfl_xor(v, 1, 64);
          float mag = sqrtf(v * v + o * o);
          float s = (mag > LAM_) ? (mag - LAM_) / (mag + 1e-8f) : 0.f;
          v *= s;
        }
        if (MULPT) v *= bf2f(ptb[(size_t)row * Dout + col]);
        if (colok) {
          if (PEW) {
            int t = row % T_;
            float freq = expf((float)(col & ~1) * (-9.210340371976184f / 256.0f));
            float ang = (float)t * freq;
            float pe = (col & 1) ? cosf(ang) : sinf(ang);
            float h = v + pe;
            Cf[(size_t)row * Dout + col] = h;
            Cf[(size_t)row * Dout + col + (size_t)NT_ * D_] = h;
          } else if (OUTBF) {
            Cb[(size_t)row * Dout + col] = f2bf(v);
          } else {
            Cf[(size_t)row * Dout + col] = v;
          }
        }
      }
    }
  }
}

// ---------------------------------------------------------------- Tw GEMM + residual + LayerNorm fused
// x32 = LN(gp @ Tw^T + Tb + x32) * lng + lnb, in place. Block: 64 rows x 256
// cols (full LN row), 4 waves = 2 row-halves x 2 col-halves; each wave 2x8
// 16x16 frags. K=256 in 4 BK=64 steps (R2 sync structure). Row stats: shfl
// over 16-lane col group + cross-wave exchange via LDS (As reused, 1 KB).
__global__ __launch_bounds__(256) void twln_kernel(
    const unsigned short* __restrict__ A,
    const unsigned short* __restrict__ W0, const unsigned short* __restrict__ W1,
    const float* __restrict__ b0, const float* __restrict__ b1,
    const float* __restrict__ lg0, const float* __restrict__ lb0,
    const float* __restrict__ lg1, const float* __restrict__ lb1,
    float* __restrict__ x32) {
  __shared__ __align__(16) unsigned short As[2][64 * 32];    // 8 KB
  __shared__ __align__(16) unsigned short Bs[2][256 * 32];   // 32 KB
  const int tid = threadIdx.x, w = tid >> 6, lane = tid & 63;
  const int quad = lane >> 4, r16 = lane & 15;
  const int rh = w >> 1, ch = w & 1;
  const int by = blockIdx.x;
  const int tower = (by >= 252) ? 1 : 0;
  const unsigned short* W = tower ? W1 : W0;
  const float* bias = tower ? b1 : b0;
  const float* lng = tower ? lg1 : lg0;
  const float* lnb = tower ? lb1 : lb0;

  const unsigned short* gA = A + (size_t)(by * 64 + (tid >> 2)) * 256 + (tid & 3) * 8;
  const unsigned short* gW = W + (size_t)(tid >> 2) * 256 + (tid & 3) * 8;

  f32x4 acc[2][8];
  #pragma unroll
  for (int i = 0; i < 2; ++i)
    #pragma unroll
    for (int j = 0; j < 8; ++j)
      #pragma unroll
      for (int r = 0; r < 4; ++r) acc[i][j][r] = 0.f;

  for (int ks = 0; ks < 4; ++ks) {
    #pragma unroll
    for (int p = 0; p < 2; ++p)
      async_copy16(gA + p * 32, (char*)As + p * 4096 + tid * 16);
    #pragma unroll
    for (int p = 0; p < 2; ++p)
      #pragma unroll
      for (int k = 0; k < 4; ++k)
        async_copy16(gW + (size_t)k * 16384 + p * 32,
                     (char*)Bs + p * 16384 + k * 4096 + tid * 16);
    gA += 64; gW += 64;
    __syncthreads();
    #pragma unroll
    for (int p = 0; p < 2; ++p) {
      const unsigned short* pa = As[p] + (rh * 32 + r16) * 32 + quad * 8;
      const unsigned short* pb = Bs[p] + (ch * 128 + r16) * 32 + quad * 8;
      short8 af[2], bfv[8];
      #pragma unroll
      for (int i = 0; i < 2; ++i) af[i] = *reinterpret_cast<const short8*>(pa + i * 512);
      #pragma unroll
      for (int j = 0; j < 8; ++j) bfv[j] = *reinterpret_cast<const short8*>(pb + j * 512);
      #pragma unroll
      for (int i = 0; i < 2; ++i)
        #pragma unroll
        for (int j = 0; j < 8; ++j)
          acc[i][j] = __builtin_amdgcn_mfma_f32_16x16x32_bf16(af[i], bfv[j], acc[i][j], 0, 0, 0);
    }
    __syncthreads();
  }

  const int rowb = by * 64 + rh * 32 + quad * 4;
  const int colb = ch * 128 + r16;
  float s[2][4], sq[2][4];
  #pragma unroll
  for (int i = 0; i < 2; ++i)
    #pragma unroll
    for (int r = 0; r < 4; ++r) { s[i][r] = 0.f; sq[i][r] = 0.f; }
  #pragma unroll
  for (int j = 0; j < 8; ++j) {
    int col = colb + j * 16;
    float bv = bias[col];
    #pragma unroll
    for (int i = 0; i < 2; ++i)
      #pragma unroll
      for (int r = 0; r < 4; ++r) {
        int row = rowb + i * 16 + r;
        float h = acc[i][j][r] + bv + x32[(size_t)row * 256 + col];
        acc[i][j][r] = h;
        s[i][r] += h;
        sq[i][r] += h * h;
      }
  }
  #pragma unroll
  for (int off = 1; off < 16; off <<= 1)
    #pragma unroll
    for (int i = 0; i < 2; ++i)
      #pragma unroll
      for (int r = 0; r < 4; ++r) {
        s[i][r]  += __shfl_xor(s[i][r],  off, 64);
        sq[i][r] += __shfl_xor(sq[i][r], off, 64);
      }
  float* red = (float*)As;   // 64 rows x {sum0, sq0, sum1, sq1} = 1 KB (As free)
  if (r16 == 0) {
    #pragma unroll
    for (int i = 0; i < 2; ++i)
      #pragma unroll
      for (int r = 0; r < 4; ++r) {
        int lr = rh * 32 + i * 16 + quad * 4 + r;
        red[lr * 4 + ch * 2]     = s[i][r];
        red[lr * 4 + ch * 2 + 1] = sq[i][r];
      }
  }
  __syncthreads();
  #pragma unroll
  for (int i = 0; i < 2; ++i)
    #pragma unroll
    for (int r = 0; r < 4; ++r) {
      int lr = rh * 32 + i * 16 + quad * 4 + r;
      float tot = red[lr * 4] + red[lr * 4 + 2];
      float tsq = red[lr * 4 + 1] + red[lr * 4 + 3];
      float mu = tot * (1.0f / 256.0f);
      float var = tsq * (1.0f / 256.0f) - mu * mu;
      float is = rsqrtf(var + 1e-5f);
      int row = rowb + i * 16 + r;
      #pragma unroll
      for (int j = 0; j < 8; ++j) {
        int col = colb + j * 16;
        x32[(size_t)row * 256 + col] = (acc[i][j][r] - mu) * is * lng[col] + lnb[col];
      }
    }
}

// ---------------------------------------------------------------- norm
__global__ __launch_bounds__(256) void norm_kernel(const float* __restrict__ x,
    float* __restrict__ xn, float* __restrict__ meanb, float* __restrict__ stdb) {
  __shared__ float red[4];
  int bm = blockIdx.x;
  const float* xr = x + (size_t)bm * L_;
  float v0 = xr[threadIdx.x], v1 = xr[threadIdx.x + 256];
  float mu = block_sum256(v0 + v1, red) * (1.0f / L_);
  float d0 = v0 - mu, d1 = v1 - mu;
  float sd = sqrtf(block_sum256(d0 * d0 + d1 * d1, red) * (1.0f / L_));
  float inv = 1.0f / (sd + 1e-5f);
  float* xo = xn + (size_t)bm * L_;
  xo[threadIdx.x] = d0 * inv;
  xo[threadIdx.x + 256] = d1 * inv;
  if (threadIdx.x == 0) { meanb[bm] = mu; stdb[bm] = sd; }
}

// ---------------------------------------------------------------- im2col -> bf16 K=352
__global__ __launch_bounds__(256) void im2col_kernel(const float* __restrict__ xn,
                                                     unsigned short* __restrict__ im) {
  int row = blockIdx.x;
  int b = row / T_, t = row - b * T_;
  const float* xb = xn + (size_t)b * M_ * L_ + t * 8;
  unsigned short* o = im + (size_t)row * KCP_;
  for (int i = threadIdx.x; i < KCP_; i += 256) {
    float v = 0.f;
    if (i < 336) { int m = i >> 4, p = i & 15; v = xb[m * L_ + p]; }
    o[i] = f2bf(v);
  }
}

// ---------------------------------------------------------------- DFT along T (rfft)
__global__ __launch_bounds__(256) void dft_kernel(const float* __restrict__ X,
                                                  unsigned short* __restrict__ Zcat) {
  __shared__ float2 tw[T_ * F_];     // 15.75 KB
  int bt = blockIdx.x, d = threadIdx.x;
  for (int i = threadIdx.x; i < T_ * F_; i += 256) {
    int t = i >> 5, f = i & 31;
    int k = (f * t) % T_;
    float sn, cs;
    sincosf((6.283185307179586f / 63.0f) * (float)k, &sn, &cs);
    tw[i] = make_float2(cs, -sn);
  }
  __syncthreads();
  const float* xb = X + (size_t)bt * T_ * D_ + d;
  float ar[F_], ai[F_];
  #pragma unroll
  for (int f = 0; f < F_; ++f) { ar[f] = 0.f; ai[f] = 0.f; }
  for (int t = 0; t < T_; ++t) {
    float v = xb[(size_t)t * D_];
    const float2* w = &tw[t * F_];
    #pragma unroll
    for (int f = 0; f < F_; ++f) {
      float2 c = w[f];
      ar[f] = fmaf(v, c.x, ar[f]);
      ai[f] = fmaf(v, c.y, ai[f]);
    }
  }
  u32* z = reinterpret_cast<u32*>(Zcat + (size_t)bt * F_ * 512);
  #pragma unroll
  for (int f = 0; f < F_; ++f)
    z[f * 256 + d] = (u32)f2bf(ar[f]) | ((u32)f2bf(ai[f]) << 16);
}

// ---------------------------------------------------------------- irfft(n=63) -> pt bf16 (bf16 packed input)
__global__ __launch_bounds__(256) void irfft_kernel(const unsigned short* __restrict__ Y,
                                                    unsigned short* __restrict__ ptb) {
  __shared__ float2 tw[T_ * 31];     // 15.26 KB
  int bt = blockIdx.x, d = threadIdx.x;
  for (int i = threadIdx.x; i < T_ * 31; i += 256) {
    int t = i / 31, f = i - t * 31 + 1;
    int k = (f * t) % T_;
    float sn, cs;
    sincosf((6.283185307179586f / 63.0f) * (float)k, &sn, &cs);
    tw[i] = make_float2(cs * (2.0f / 63.0f), -sn * (2.0f / 63.0f));
  }
  __syncthreads();
  const unsigned short* yb = Y + (size_t)bt * F_ * 512 + 2 * d;
  float y0 = bf2f(yb[0]) * (1.0f / 63.0f);   // f=0: Re only
  float yr[31], yi[31];
  #pragma unroll
  for (int f = 1; f < F_; ++f) {
    u32 p = *reinterpret_cast<const u32*>(yb + (size_t)f * 512);
    yr[f - 1] = bf2f((unsigned short)(p & 0xffff));
    yi[f - 1] = bf2f((unsigned short)(p >> 16));
  }
  unsigned short* po = ptb + (size_t)bt * T_ * D_ + d;
  for (int t = 0; t < T_; ++t) {
    const float2* w = &tw[t * 31];
    float acc0 = y0, acc1 = 0.f;
    #pragma unroll
    for (int f = 0; f < 31; f += 2) {
      float2 c = w[f];
      acc0 = fmaf(yr[f], c.x, fmaf(yi[f], c.y, acc0));
      if (f + 1 < 31) {
        float2 c1 = w[f + 1];
        acc1 = fmaf(yr[f + 1], c1.x, fmaf(yi[f + 1], c1.y, acc1));
      }
    }
    po[(size_t)t * D_] = f2bf(acc0 + acc1);
  }
}

// ---------------------------------------------------------------- gate + blend -> bf16 feat (wave per row)
__global__ __launch_bounds__(256) void gate_feat_kernel(const float* __restrict__ x32,
    const float* __restrict__ gw, const float* __restrict__ gb,
    unsigned short* __restrict__ featbf) {
  int row = blockIdx.x * 4 + (threadIdx.x >> 6);
  int lane = threadIdx.x & 63;
  size_t base = (size_t)row * D_ + lane * 4;
  float4 tv = *reinterpret_cast<const float4*>(x32 + base);
  float4 sv = *reinterpret_cast<const float4*>(x32 + base + (size_t)NT_ * D_);
  float4 gv = *reinterpret_cast<const float4*>(gw + lane * 4);
  float dot = wave_sum(tv.x * gv.x + tv.y * gv.y + tv.z * gv.z + tv.w * gv.w) + gb[0];
  float gate = 1.0f / (1.0f + expf(-dot));
  ushort4 o;
  o.x = f2bf(gate * tv.x + (1.0f - gate) * sv.x);
  o.y = f2bf(gate * tv.y + (1.0f - gate) * sv.y);
  o.z = f2bf(gate * tv.z + (1.0f - gate) * sv.z);
  o.w = f2bf(gate * tv.w + (1.0f - gate) * sv.w);
  *reinterpret_cast<ushort4*>(featbf + base) = o;
}

// ---------------------------------------------------------------- split-K reduce + bias + rescale
__global__ __launch_bounds__(256) void final_kernel(const float* __restrict__ part,
    const float* __restrict__ pb, const float* __restrict__ stdb,
    const float* __restrict__ meanb, float* __restrict__ y) {
  int i = blockIdx.x * 256 + threadIdx.x;         // 516096
  float acc = 0.f;
  #pragma unroll
  for (int z = 0; z < PZ_; ++z) acc += part[(size_t)z * 516096 + i];
  int b = i / 2016;
  int col = i - b * 2016;
  int m = col / H_;
  float sc = stdb[b * M_ + m] + 1e-5f;
  y[i] = (acc + pb[col]) * sc + meanb[b * M_ + m];
}

// ---------------------------------------------------------------- launch
extern "C" void kernel_launch(void* const* d_in, const int* in_sizes, int n_in,
                              void* d_out, int out_size, void* d_ws, size_t ws_size,
                              hipStream_t stream) {
  const float* x      = (const float*)d_in[0];
  const float* conv_w = (const float*)d_in[1];
  const float* conv_b = (const float*)d_in[2];
  const float* tP[16];
  const float* sP[16];
  for (int i = 0; i < 16; ++i) tP[i] = (const float*)d_in[3 + i];
  for (int i = 0; i < 16; ++i) sP[i] = (const float*)d_in[19 + i];
  const float* gate_w = (const float*)d_in[35];
  const float* gate_b = (const float*)d_in[36];
  const float* proj_w = (const float*)d_in[37];
  const float* proj_b = (const float*)d_in[38];
  float* out = (float*)d_out;

  // ---- workspace (floats): total 27,646,480 f = 110.6 MB
  float* ws    = (float*)d_ws;
  float* x32   = ws;                               // 8,257,536 (2 towers x NT x D)
  unsigned short* wb = (unsigned short*)(x32 + 8257536);  // 5,201,920 shorts
  float* meanb = x32 + 8257536 + 2600960;          // 5,376
  float* stdb  = meanb + 5376;                     // 5,376
  float* R1    = stdb + 5376 + 16;                 // 8,388,608
  float* R2    = R1 + 8388608;                     // 8,388,608

  unsigned short* im2colB = (unsigned short*)R1;             // pre-loop
  unsigned short* Zcat    = (unsigned short*)R1;             // dft -> H1
  unsigned short* Ycat1   = (unsigned short*)(R1 + 4194304); // H1 -> H2
  unsigned short* ptb     = (unsigned short*)(R1 + 4194304); // irfft -> Gp
  unsigned short* gp      = (unsigned short*)R1;             // Gp -> TwLN
  unsigned short* featbf  = (unsigned short*)R1;             // post-loop

  float* xn     = R2;                              // pre-loop
  unsigned short* Ycat2b = (unsigned short*)R2;    // H2 -> irfft (bf16 packed)
  unsigned short* hidB = (unsigned short*)R2;      // Ge -> Gp
  float* part   = R2;                              // proj partials (16 x 516096 = 8.26M f)

  unsigned short* convW = wb;                      // 256*352
  unsigned short* sets  = wb + 90112;              // 6 * (Gew 131072 + Gpw 131072 + Tw 65536)
  unsigned short* catW  = wb + 90112 + 1966080;    // 12 * 262144

  // ---- weight prep
  CvtArgs ca; int blk0 = 0, ne = 0;
  auto add_ent = [&](const float* s, unsigned short* d, int rows, int scol, int dcol) {
    ca.e[ne].src = s; ca.e[ne].dst = d; ca.e[ne].rows = rows;
    ca.e[ne].scol = scol; ca.e[ne].dcol = dcol; ca.e[ne].blk0 = blk0;
    blk0 += (rows * dcol + 255) / 256; ++ne;
  };
  add_ent(conv_w, convW, 256, 336, 352);
  for (int tw = 0; tw < 2; ++tw) {
    const float** Pp = tw ? (const float**)sP : (const float**)tP;
    for (int l = 0; l < 3; ++l) {
      unsigned short* sb = sets + (size_t)(tw * 3 + l) * 327680;
      add_ent(Pp[2] + (size_t)l * 131072, sb,          512, 256, 256);  // Gew
      add_ent(Pp[4] + (size_t)l * 131072, sb + 131072, 256, 512, 512);  // Gpw
      add_ent(Pp[0] + (size_t)l * 65536,  sb + 262144, 256, 256, 256);  // Tw
    }
  }
  ca.nent = ne;
  wprep_kernel<<<blk0, 256, 0, stream>>>(ca);

  CatArgs cat;
  for (int tw = 0; tw < 2; ++tw) {
    const float** Pp = tw ? (const float**)sP : (const float**)tP;
    for (int l = 0; l < 3; ++l) {
      int e0 = (tw * 3 + l) * 2;
      cat.wr[e0]     = Pp[6]  + (size_t)l * 65536;   // H1Wr
      cat.wi[e0]     = Pp[7]  + (size_t)l * 65536;   // H1Wi
      cat.wr[e0 + 1] = Pp[10] + (size_t)l * 65536;   // H2Wr
      cat.wi[e0 + 1] = Pp[11] + (size_t)l * 65536;   // H2Wi
    }
  }
  wcat_kernel<<<12 * 1024, 256, 0, stream>>>(cat, catW);

  // ---- stem (conv epilogue adds PE and dual-writes both tower slots of x32)
  norm_kernel<<<B_ * M_, 256, 0, stream>>>(x, xn, meanb, stdb);
  im2col_kernel<<<NT_, 256, 0, stream>>>(xn, im2colB);
  mm_kernel<0, 0, 0, 11, 0, 0, 0, 0, 0, 32, 2, 1><<<dim3(2, 252), 256, 0, stream>>>(
      im2colB, convW, convW, nullptr, conv_b, conv_b, nullptr, x32,
      KCP_, 256, 0, 1 << 30, 0, 0);

  // ---- layers (both towers batched; freq branch first, then MLP with x pt fuse)
  for (int l = 0; l < 3; ++l) {
    unsigned short* st0 = sets + (size_t)l * 327680;
    unsigned short* st1 = sets + (size_t)(3 + l) * 327680;
    unsigned short* c1t0 = catW + (size_t)((0 + l) * 2) * 262144;
    unsigned short* c2t0 = c1t0 + 262144;
    unsigned short* c1t1 = catW + (size_t)((3 + l) * 2) * 262144;
    unsigned short* c2t1 = c1t1 + 262144;

    dft_kernel<<<2 * B_, 256, 0, stream>>>(x32, Zcat);
    mm_kernel<0, 1, 1, 8, 0, 0, 1, 0, 0, 64, 2, 0><<<dim3(4, 256), 256, 0, stream>>>(
        Zcat, c1t0, c1t1, nullptr, tP[9] + (size_t)l * D_, sP[9] + (size_t)l * D_,
        nullptr, Ycat1, 512, 512, 0, 128, 0, 0);
    mm_kernel<0, 1, 1, 8, 0, 0, 0, 0, 0, 64, 2, 0><<<dim3(4, 256), 256, 0, stream>>>(
        Ycat1, c2t0, c2t1, nullptr, tP[13] + (size_t)l * D_, sP[13] + (size_t)l * D_,
        nullptr, Ycat2b, 512, 512, 0, 128, 0, 0);
    irfft_kernel<<<2 * B_, 256, 0, stream>>>(Ycat2b, ptb);
    mm_kernel<1, 1, 0, 4, 1, 0, 0, 0, 0, 64, 2, 0><<<dim3(4, 504), 256, 0, stream>>>(
        x32, st0, st1, nullptr, tP[3] + (size_t)l * HID_, sP[3] + (size_t)l * HID_,
        nullptr, hidB, 256, 512, 0, 252, 0, 0);
    mm_kernel<0, 1, 0, 8, 0, 0, 0, 1, 0, 64, 2, 0><<<dim3(2, 504), 256, 0, stream>>>(
        hidB, st0 + 131072, st1 + 131072, nullptr,
        tP[5] + (size_t)l * D_, sP[5] + (size_t)l * D_, ptb, gp, 512, 256, 0, 252, 0, 0);
    twln_kernel<<<504, 256, 0, stream>>>(
        gp, st0 + 262144, st1 + 262144,
        tP[1] + (size_t)l * D_, sP[1] + (size_t)l * D_,
        tP[14] + (size_t)l * D_, tP[15] + (size_t)l * D_,
        sP[14] + (size_t)l * D_, sP[15] + (size_t)l * D_, x32);
  }

  // ---- head
  gate_feat_kernel<<<NT_ / 4, 256, 0, stream>>>(x32, gate_w, gate_b, featbf);
  // proj: BK=64, A async bf16 + W fp32 reg-staged, PZ=16 z-blocks of 16
  // k64-steps (last z takes 12; totk=252 in BK units). R2 known-best config.
  mm_kernel<0, 0, 2, 0, 0, 1, 0, 0, 1, 64, 2, 0><<<dim3(16, 4, PZ_), 256, 0, stream>>>(
      featbf, nullptr, nullptr, proj_w, nullptr, nullptr, nullptr, part,
      NT_, 2016, 16, 1 << 30, 256, 252);
  final_kernel<<<2016, 256, 0, stream>>>(part, proj_b, stdb, meanb, out);
}

// Round 8
// 957.905 us; speedup vs baseline: 1.1643x; 1.0273x over previous
//
#include <hip/hip_runtime.h>
#include <cstddef>
#include <cstdint>

#define B_    256
#define M_    21
#define L_    512
#define D_    256
#define T_    63
#define F_    32
#define NT_   16128   // B_*T_
#define HID_  512
#define KCP_  352     // M_*P_=336 padded to 32
#define H_    96
#define LAM_  0.01f
#define PZ_   16      // proj split-K z-blocks (BK=64: 16 k64-steps each, last z takes 12)

typedef __attribute__((ext_vector_type(8))) short short8;
typedef __attribute__((ext_vector_type(4))) float f32x4;
typedef unsigned int u32;
typedef const u32 __attribute__((address_space(1)))* gas1_t;
typedef u32 __attribute__((address_space(3)))* las3_t;

__device__ __forceinline__ void async_copy16(const void* g, void* l) {
  __builtin_amdgcn_global_load_lds((gas1_t)g, (las3_t)(uintptr_t)l, 16, 0, 0);
}
__device__ __forceinline__ unsigned short f2bf(float x) {   // RNE
  unsigned u = __float_as_uint(x);
  return (unsigned short)((u + 0x7FFF + ((u >> 16) & 1)) >> 16);
}
__device__ __forceinline__ float bf2f(unsigned short u) {
  return __uint_as_float(((unsigned)u) << 16);
}
__device__ __forceinline__ float gelu_exact(float v) {
  return 0.5f * v * (1.0f + erff(v * 0.70710678118654752f));
}
__device__ __forceinline__ float block_sum256(float v, float* red4) {
  #pragma unroll
  for (int off = 32; off > 0; off >>= 1) v += __shfl_down(v, off, 64);
  if ((threadIdx.x & 63) == 0) red4[threadIdx.x >> 6] = v;
  __syncthreads();
  float r = red4[0] + red4[1] + red4[2] + red4[3];
  __syncthreads();
  return r;
}
__device__ __forceinline__ float wave_sum(float v) {
  #pragma unroll
  for (int off = 1; off < 64; off <<= 1) v += __shfl_xor(v, off, 64);
  return v;
}

// ---------------------------------------------------------------- weight prep
struct CvtEnt { const float* src; unsigned short* dst; int rows, scol, dcol, blk0; };
struct CvtArgs { CvtEnt e[19]; int nent; };
__global__ __launch_bounds__(256) void wprep_kernel(CvtArgs a) {
  int blk = blockIdx.x, e = 0;
  while (e + 1 < a.nent && a.e[e + 1].blk0 <= blk) ++e;
  CvtEnt en = a.e[e];
  int idx = (blk - en.blk0) * 256 + threadIdx.x;
  int total = en.rows * en.dcol;
  if (idx >= total) return;
  int r = idx / en.dcol, c = idx - r * en.dcol;
  float v = (c < en.scol) ? en.src[(size_t)r * en.scol + c] : 0.f;
  en.dst[idx] = f2bf(v);
}

// interleaved cat weight: row 2c+p, col 2d+q
struct CatArgs { const float* wr[12]; const float* wi[12]; };
__global__ __launch_bounds__(256) void wcat_kernel(CatArgs a, unsigned short* dst) {
  int e = blockIdx.x >> 10;
  int idx = ((blockIdx.x & 1023) << 8) + threadIdx.x;
  int r = idx >> 9, c = idx & 511;
  int cp = r >> 1, p = r & 1, d = c >> 1, q = c & 1;
  const float* wr = a.wr[e];
  const float* wi = a.wi[e];
  float v;
  if (p == 0) v = (q == 0) ? wr[cp * 256 + d] : -wi[cp * 256 + d];
  else        v = (q == 0) ? wi[cp * 256 + d] :  wr[cp * 256 + d];
  dst[(size_t)e * 262144 + idx] = f2bf(v);
}

// ---------------------------------------------------------------- MFMA GEMM
// C = A @ W^T (+bias). Block tile (32*RT) x 128, 4 waves (2x2), each wave
// RT x 4 of 16x16x32-bf16 MFMA. BK = 32 or 64, LDS as [BK/32][rows][32] panels.
// BIASM: 0 normal, 1 interleaved clin (odd col: 2*bi[col>>1]), 2 none+col guard.
// CVTA/CVTW: stage from fp32 with depth-1 register prefetch.
// PEW: conv stem epilogue -- add positional encoding (writes t-tower only;
// layer-0 consumers share via asub).
// asub: element offset subtracted from A base for tower-1 blocks (layer-0
// tower dedup: both towers read identical t-tower data).
template <int ACT, int OUTBF, int BIASM, int KSTEPS, int CVTA, int CVTW,
          int SHRINK, int MULPT, int SPLITK, int BK, int RT, int PEW>
__global__ __launch_bounds__(256) void mm_kernel(
    const void* __restrict__ Av,
    const unsigned short* __restrict__ W0, const unsigned short* __restrict__ W1,
    const float* __restrict__ Wf,
    const float* __restrict__ b0, const float* __restrict__ b1,
    const unsigned short* __restrict__ ptb,
    void* __restrict__ Cv,
    const int K, const int Dout, const int ksteps_rt, const int yhalf,
    const int prow, const int totk, const int asub) {
  constexpr int NP = BK / 32;
  constexpr int RWS = 32 * RT;
  __shared__ __align__(16) unsigned short As[NP * RWS * 32];
  __shared__ __align__(16) unsigned short Bs[NP * 128 * 32];
  const int tid = threadIdx.x, w = tid >> 6, lane = tid & 63;
  const int quad = lane >> 4, r16 = lane & 15;
  int nks = KSTEPS ? KSTEPS : ksteps_rt;
  const int ksbeg = SPLITK ? (int)blockIdx.z * nks : 0;
  if (SPLITK) { int rem = totk - ksbeg; if (nks > rem) nks = rem; }
  const int kst = ksbeg * BK;
  const int tower = ((int)blockIdx.y >= yhalf) ? 1 : 0;
  const long long ao = tower ? (long long)asub : 0;
  const unsigned short* Wb = tower ? W1 : W0;
  const float* bias = tower ? b1 : b0;

  const unsigned short* Ab = (const unsigned short*)Av;
  const float* Af = (const float*)Av;
  const unsigned short* gA = nullptr;
  unsigned short* lA = As + (w * 8 * RT) * 32;
  if (!CVTA) gA = Ab + ((size_t)((int)blockIdx.y * RWS + w * 8 * RT + (lane >> 2)) * K
                     + kst + (lane & 3) * 8) - ao;
  const unsigned short* gB = nullptr;
  unsigned short* lB = Bs + (w * 32) * 32;
  if (!CVTW) gB = Wb + (size_t)((int)blockIdx.x * 128 + w * 32 + (lane >> 2)) * K
                     + kst + (lane & 3) * 8;
  // CVT mapping: 8 lanes per row (128B contiguous), rows crow+32*rr.
  const int crow = tid >> 3;            // 0..31
  const int ck4  = (tid & 7) << 2;      // 0,4,..,28

  float4 areg[NP][RT];
  float4 wreg[NP][4];
  auto loadA = [&](int ksi) {
    #pragma unroll
    for (int p = 0; p < NP; ++p)
      #pragma unroll
      for (int rr = 0; rr < RT; ++rr)
        areg[p][rr] = *reinterpret_cast<const float4*>(
            Af + ((size_t)((int)blockIdx.y * RWS + crow + 32 * rr) * K
               + kst + ksi * BK + p * 32 + ck4) - ao);
  };
  auto loadW = [&](int ksi) {
    #pragma unroll
    for (int p = 0; p < NP; ++p)
      #pragma unroll
      for (int rr = 0; rr < 4; ++rr) {
        int wrow = (int)blockIdx.x * 128 + crow + 32 * rr;
        if (wrow >= Dout) wrow = Dout - 1;
        wreg[p][rr] = *reinterpret_cast<const float4*>(
            Wf + (size_t)wrow * K + kst + ksi * BK + p * 32 + ck4);
      }
  };
  if (CVTA) loadA(0);
  if (CVTW) loadW(0);

  f32x4 acc[RT][4];
  #pragma unroll
  for (int i = 0; i < RT; ++i)
    #pragma unroll
    for (int j = 0; j < 4; ++j)
      #pragma unroll
      for (int r = 0; r < 4; ++r) acc[i][j][r] = 0.f;

  for (int ks = 0; ks < nks; ++ks) {
    if (!CVTA) {
      #pragma unroll
      for (int p = 0; p < NP; ++p)
        #pragma unroll
        for (int c = 0; c < RT / 2; ++c)
          async_copy16(gA + (size_t)(c * 16) * K + p * 32,
                       lA + p * (RWS * 32) + c * 16 * 32);
      gA += BK;
    } else {
      #pragma unroll
      for (int p = 0; p < NP; ++p)
        #pragma unroll
        for (int rr = 0; rr < RT; ++rr) {
          float4 v = areg[p][rr];
          ushort4 o; o.x = f2bf(v.x); o.y = f2bf(v.y); o.z = f2bf(v.z); o.w = f2bf(v.w);
          *reinterpret_cast<ushort4*>(As + p * (RWS * 32) + (crow + 32 * rr) * 32 + ck4) = o;
        }
    }
    if (!CVTW) {
      #pragma unroll
      for (int p = 0; p < NP; ++p) {
        async_copy16(gB + p * 32, lB + p * 4096);
        async_copy16(gB + (size_t)16 * K + p * 32, lB + p * 4096 + 16 * 32);
      }
      gB += BK;
    } else {
      #pragma unroll
      for (int p = 0; p < NP; ++p)
        #pragma unroll
        for (int rr = 0; rr < 4; ++rr) {
          float4 v = wreg[p][rr];
          ushort4 o; o.x = f2bf(v.x); o.y = f2bf(v.y); o.z = f2bf(v.z); o.w = f2bf(v.w);
          *reinterpret_cast<ushort4*>(Bs + p * 4096 + (crow + 32 * rr) * 32 + ck4) = o;
        }
    }
    __syncthreads();
    if (CVTA && ks + 1 < nks) loadA(ks + 1);
    if (CVTW && ks + 1 < nks) loadW(ks + 1);
    #pragma unroll
    for (int p = 0; p < NP; ++p) {
      const unsigned short* pa = As + p * (RWS * 32) + ((w >> 1) * 16 * RT + r16) * 32 + quad * 8;
      const unsigned short* pb = Bs + p * 4096 + (64 * (w & 1) + r16) * 32 + quad * 8;
      short8 af[RT], bfv[4];
      #pragma unroll
      for (int i = 0; i < RT; ++i) af[i] = *reinterpret_cast<const short8*>(pa + i * 512);
      #pragma unroll
      for (int j = 0; j < 4; ++j) bfv[j] = *reinterpret_cast<const short8*>(pb + j * 512);
      #pragma unroll
      for (int i = 0; i < RT; ++i)
        #pragma unroll
        for (int j = 0; j < 4; ++j)
          acc[i][j] = __builtin_amdgcn_mfma_f32_16x16x32_bf16(af[i], bfv[j], acc[i][j], 0, 0, 0);
    }
    __syncthreads();
  }

  float* Cf = (float*)Cv;
  unsigned short* Cb = (unsigned short*)Cv;
  if (SPLITK) Cf += (size_t)blockIdx.z * prow * Dout;
  const int colb = (int)blockIdx.x * 128 + 64 * (w & 1) + r16;
  const int rowb = (int)blockIdx.y * RWS + 16 * RT * (w >> 1) + quad * 4;
  #pragma unroll
  for (int j = 0; j < 4; ++j) {
    int col = colb + 16 * j;
    float bv = 0.f;
    if (BIASM == 0) bv = bias[col];
    else if (BIASM == 1) bv = (col & 1) ? 2.0f * bias[col >> 1] : 0.f;
    bool colok = (BIASM != 2) || (col < Dout);
    #pragma unroll
    for (int i = 0; i < RT; ++i) {
      #pragma unroll
      for (int r = 0; r < 4; ++r) {
        int row = rowb + 16 * i + r;
        float v = acc[i][j][r] + bv;
        if (ACT == 1) v = gelu_exact(v);
        if (SHRINK) {
          float o = __shfl_xor(v, 1, 64);
          float mag = sqrtf(v * v + o * o);
          float s = (mag > LAM_) ? (mag - LAM_) / (mag + 1e-8f) : 0.f;
          v *= s;
        }
        if (MULPT) v *= bf2f(ptb[(size_t)row * Dout + col]);
        if (colok) {
          if (PEW) {
            int t = row % T_;
            float freq = expf((float)(col & ~1) * (-9.210340371976184f / 256.0f));
            float ang = (float)t * freq;
            float pe = (col & 1) ? cosf(ang) : sinf(ang);
            Cf[(size_t)row * Dout + col] = v + pe;   // t-tower only (l0 dedup)
          } else if (OUTBF) {
            Cb[(size_t)row * Dout + col] = f2bf(v);
          } else {
            Cf[(size_t)row * Dout + col] = v;
          }
        }
      }
    }
  }
}

// ---------------------------------------------------------------- Tw GEMM + residual + LayerNorm fused
// x32 = LN(gp @ Tw^T + Tb + x32) * lng + lnb, in place. Block: 64 rows x 256
// cols (full LN row), 4 waves = 2 row-halves x 2 col-halves; each wave 2x8
// 16x16 frags. K=256 in 4 BK=64 steps. ressub: residual-read element offset
// for tower-1 blocks (layer-0 dedup).
__global__ __launch_bounds__(256) void twln_kernel(
    const unsigned short* __restrict__ A,
    const unsigned short* __restrict__ W0, const unsigned short* __restrict__ W1,
    const float* __restrict__ b0, const float* __restrict__ b1,
    const float* __restrict__ lg0, const float* __restrict__ lb0,
    const float* __restrict__ lg1, const float* __restrict__ lb1,
    float* __restrict__ x32, const int ressub) {
  __shared__ __align__(16) unsigned short As[2][64 * 32];    // 8 KB
  __shared__ __align__(16) unsigned short Bs[2][256 * 32];   // 32 KB
  const int tid = threadIdx.x, w = tid >> 6, lane = tid & 63;
  const int quad = lane >> 4, r16 = lane & 15;
  const int rh = w >> 1, ch = w & 1;
  const int by = blockIdx.x;
  const int tower = (by >= 252) ? 1 : 0;
  const long long ro = tower ? (long long)ressub : 0;
  const unsigned short* W = tower ? W1 : W0;
  const float* bias = tower ? b1 : b0;
  const float* lng = tower ? lg1 : lg0;
  const float* lnb = tower ? lb1 : lb0;

  const unsigned short* gA = A + (size_t)(by * 64 + (tid >> 2)) * 256 + (tid & 3) * 8;
  const unsigned short* gW = W + (size_t)(tid >> 2) * 256 + (tid & 3) * 8;

  f32x4 acc[2][8];
  #pragma unroll
  for (int i = 0; i < 2; ++i)
    #pragma unroll
    for (int j = 0; j < 8; ++j)
      #pragma unroll
      for (int r = 0; r < 4; ++r) acc[i][j][r] = 0.f;

  for (int ks = 0; ks < 4; ++ks) {
    #pragma unroll
    for (int p = 0; p < 2; ++p)
      async_copy16(gA + p * 32, (char*)As + p * 4096 + tid * 16);
    #pragma unroll
    for (int p = 0; p < 2; ++p)
      #pragma unroll
      for (int k = 0; k < 4; ++k)
        async_copy16(gW + (size_t)k * 16384 + p * 32,
                     (char*)Bs + p * 16384 + k * 4096 + tid * 16);
    gA += 64; gW += 64;
    __syncthreads();
    #pragma unroll
    for (int p = 0; p < 2; ++p) {
      const unsigned short* pa = As[p] + (rh * 32 + r16) * 32 + quad * 8;
      const unsigned short* pb = Bs[p] + (ch * 128 + r16) * 32 + quad * 8;
      short8 af[2], bfv[8];
      #pragma unroll
      for (int i = 0; i < 2; ++i) af[i] = *reinterpret_cast<const short8*>(pa + i * 512);
      #pragma unroll
      for (int j = 0; j < 8; ++j) bfv[j] = *reinterpret_cast<const short8*>(pb + j * 512);
      #pragma unroll
      for (int i = 0; i < 2; ++i)
        #pragma unroll
        for (int j = 0; j < 8; ++j)
          acc[i][j] = __builtin_amdgcn_mfma_f32_16x16x32_bf16(af[i], bfv[j], acc[i][j], 0, 0, 0);
    }
    __syncthreads();
  }

  const int rowb = by * 64 + rh * 32 + quad * 4;
  const int colb = ch * 128 + r16;
  float s[2][4], sq[2][4];
  #pragma unroll
  for (int i = 0; i < 2; ++i)
    #pragma unroll
    for (int r = 0; r < 4; ++r) { s[i][r] = 0.f; sq[i][r] = 0.f; }
  #pragma unroll
  for (int j = 0; j < 8; ++j) {
    int col = colb + j * 16;
    float bv = bias[col];
    #pragma unroll
    for (int i = 0; i < 2; ++i)
      #pragma unroll
      for (int r = 0; r < 4; ++r) {
        int row = rowb + i * 16 + r;
        float h = acc[i][j][r] + bv + x32[((size_t)row * 256 + col) - ro];
        acc[i][j][r] = h;
        s[i][r] += h;
        sq[i][r] += h * h;
      }
  }
  #pragma unroll
  for (int off = 1; off < 16; off <<= 1)
    #pragma unroll
    for (int i = 0; i < 2; ++i)
      #pragma unroll
      for (int r = 0; r < 4; ++r) {
        s[i][r]  += __shfl_xor(s[i][r],  off, 64);
        sq[i][r] += __shfl_xor(sq[i][r], off, 64);
      }
  float* red = (float*)As;   // 64 rows x {sum0, sq0, sum1, sq1} = 1 KB (As free)
  if (r16 == 0) {
    #pragma unroll
    for (int i = 0; i < 2; ++i)
      #pragma unroll
      for (int r = 0; r < 4; ++r) {
        int lr = rh * 32 + i * 16 + quad * 4 + r;
        red[lr * 4 + ch * 2]     = s[i][r];
        red[lr * 4 + ch * 2 + 1] = sq[i][r];
      }
  }
  __syncthreads();
  #pragma unroll
  for (int i = 0; i < 2; ++i)
    #pragma unroll
    for (int r = 0; r < 4; ++r) {
      int lr = rh * 32 + i * 16 + quad * 4 + r;
      float tot = red[lr * 4] + red[lr * 4 + 2];
      float tsq = red[lr * 4 + 1] + red[lr * 4 + 3];
      float mu = tot * (1.0f / 256.0f);
      float var = tsq * (1.0f / 256.0f) - mu * mu;
      float is = rsqrtf(var + 1e-5f);
      int row = rowb + i * 16 + r;
      #pragma unroll
      for (int j = 0; j < 8; ++j) {
        int col = colb + j * 16;
        x32[(size_t)row * 256 + col] = (acc[i][j][r] - mu) * is * lng[col] + lnb[col];
      }
    }
}

// ---------------------------------------------------------------- norm + im2col fused
// Per (b,m) row: compute mean/std, scatter normalized values directly into
// the im2col bf16 buffer (each l lands in <=2 overlapping P=16/S=8 windows).
// m==0 blocks zero the pad cols 336..351 for their b.
__global__ __launch_bounds__(256) void norm_kernel(const float* __restrict__ x,
    unsigned short* __restrict__ im, float* __restrict__ meanb, float* __restrict__ stdb) {
  __shared__ float red[4];
  int bm = blockIdx.x;
  int b = bm / M_, m = bm - b * M_;
  const float* xr = x + (size_t)bm * L_;
  float v0 = xr[threadIdx.x], v1 = xr[threadIdx.x + 256];
  float mu = block_sum256(v0 + v1, red) * (1.0f / L_);
  float d0 = v0 - mu, d1 = v1 - mu;
  float sd = sqrtf(block_sum256(d0 * d0 + d1 * d1, red) * (1.0f / L_));
  float inv = 1.0f / (sd + 1e-5f);
  unsigned short* imb = im + (size_t)b * T_ * KCP_ + m * 16;
  auto scat = [&](int l, float v) {
    unsigned short o = f2bf(v);
    int t0 = l >> 3, p0 = l & 7;
    if (t0 < T_) imb[(size_t)t0 * KCP_ + p0] = o;
    if (t0 >= 1) imb[(size_t)(t0 - 1) * KCP_ + p0 + 8] = o;
  };
  scat(threadIdx.x, d0 * inv);
  scat(threadIdx.x + 256, d1 * inv);
  if (m == 0) {
    unsigned short* pz = im + (size_t)b * T_ * KCP_ + 336;
    for (int i = threadIdx.x; i < T_ * 16; i += 256) {
      int t = i >> 4, c = i & 15;
      pz[(size_t)t * KCP_ + c] = 0;
    }
  }
  if (threadIdx.x == 0) { meanb[bm] = mu; stdb[bm] = sd; }
}

// ---------------------------------------------------------------- DFT along T (rfft)
__global__ __launch_bounds__(256) void dft_kernel(const float* __restrict__ X,
                                                  unsigned short* __restrict__ Zcat) {
  __shared__ float2 tw[T_ * F_];     // 15.75 KB
  int bt = blockIdx.x, d = threadIdx.x;
  for (int i = threadIdx.x; i < T_ * F_; i += 256) {
    int t = i >> 5, f = i & 31;
    int k = (f * t) % T_;
    float sn, cs;
    sincosf((6.283185307179586f / 63.0f) * (float)k, &sn, &cs);
    tw[i] = make_float2(cs, -sn);
  }
  __syncthreads();
  const float* xb = X + (size_t)bt * T_ * D_ + d;
  float ar[F_], ai[F_];
  #pragma unroll
  for (int f = 0; f < F_; ++f) { ar[f] = 0.f; ai[f] = 0.f; }
  for (int t = 0; t < T_; ++t) {
    float v = xb[(size_t)t * D_];
    const float2* w = &tw[t * F_];
    #pragma unroll
    for (int f = 0; f < F_; ++f) {
      float2 c = w[f];
      ar[f] = fmaf(v, c.x, ar[f]);
      ai[f] = fmaf(v, c.y, ai[f]);
    }
  }
  u32* z = reinterpret_cast<u32*>(Zcat + (size_t)bt * F_ * 512);
  #pragma unroll
  for (int f = 0; f < F_; ++f)
    z[f * 256 + d] = (u32)f2bf(ar[f]) | ((u32)f2bf(ai[f]) << 16);
}

// ---------------------------------------------------------------- irfft(n=63) -> pt bf16 (bf16 packed input)
__global__ __launch_bounds__(256) void irfft_kernel(const unsigned short* __restrict__ Y,
                                                    unsigned short* __restrict__ ptb) {
  __shared__ float2 tw[T_ * 31];     // 15.26 KB
  int bt = blockIdx.x, d = threadIdx.x;
  for (int i = threadIdx.x; i < T_ * 31; i += 256) {
    int t = i / 31, f = i - t * 31 + 1;
    int k = (f * t) % T_;
    float sn, cs;
    sincosf((6.283185307179586f / 63.0f) * (float)k, &sn, &cs);
    tw[i] = make_float2(cs * (2.0f / 63.0f), -sn * (2.0f / 63.0f));
  }
  __syncthreads();
  const unsigned short* yb = Y + (size_t)bt * F_ * 512 + 2 * d;
  float y0 = bf2f(yb[0]) * (1.0f / 63.0f);   // f=0: Re only
  float yr[31], yi[31];
  #pragma unroll
  for (int f = 1; f < F_; ++f) {
    u32 p = *reinterpret_cast<const u32*>(yb + (size_t)f * 512);
    yr[f - 1] = bf2f((unsigned short)(p & 0xffff));
    yi[f - 1] = bf2f((unsigned short)(p >> 16));
  }
  unsigned short* po = ptb + (size_t)bt * T_ * D_ + d;
  for (int t = 0; t < T_; ++t) {
    const float2* w = &tw[t * 31];
    float acc0 = y0, acc1 = 0.f;
    #pragma unroll
    for (int f = 0; f < 31; f += 2) {
      float2 c = w[f];
      acc0 = fmaf(yr[f], c.x, fmaf(yi[f], c.y, acc0));
      if (f + 1 < 31) {
        float2 c1 = w[f + 1];
        acc1 = fmaf(yr[f + 1], c1.x, fmaf(yi[f + 1], c1.y, acc1));
      }
    }
    po[(size_t)t * D_] = f2bf(acc0 + acc1);
  }
}

// ---------------------------------------------------------------- gate + blend -> bf16 feat (wave per row)
__global__ __launch_bounds__(256) void gate_feat_kernel(const float* __restrict__ x32,
    const float* __restrict__ gw, const float* __restrict__ gb,
    unsigned short* __restrict__ featbf) {
  int row = blockIdx.x * 4 + (threadIdx.x >> 6);
  int lane = threadIdx.x & 63;
  size_t base = (size_t)row * D_ + lane * 4;
  float4 tv = *reinterpret_cast<const float4*>(x32 + base);
  float4 sv = *reinterpret_cast<const float4*>(x32 + base + (size_t)NT_ * D_);
  float4 gv = *reinterpret_cast<const float4*>(gw + lane * 4);
  float dot = wave_sum(tv.x * gv.x + tv.y * gv.y + tv.z * gv.z + tv.w * gv.w) + gb[0];
  float gate = 1.0f / (1.0f + expf(-dot));
  ushort4 o;
  o.x = f2bf(gate * tv.x + (1.0f - gate) * sv.x);
  o.y = f2bf(gate * tv.y + (1.0f - gate) * sv.y);
  o.z = f2bf(gate * tv.z + (1.0f - gate) * sv.z);
  o.w = f2bf(gate * tv.w + (1.0f - gate) * sv.w);
  *reinterpret_cast<ushort4*>(featbf + base) = o;
}

// ---------------------------------------------------------------- split-K reduce + bias + rescale
__global__ __launch_bounds__(256) void final_kernel(const float* __restrict__ part,
    const float* __restrict__ pb, const float* __restrict__ stdb,
    const float* __restrict__ meanb, float* __restrict__ y) {
  int i = blockIdx.x * 256 + threadIdx.x;         // 516096
  float acc = 0.f;
  #pragma unroll
  for (int z = 0; z < PZ_; ++z) acc += part[(size_t)z * 516096 + i];
  int b = i / 2016;
  int col = i - b * 2016;
  int m = col / H_;
  float sc = stdb[b * M_ + m] + 1e-5f;
  y[i] = (acc + pb[col]) * sc + meanb[b * M_ + m];
}

// ---------------------------------------------------------------- launch
extern "C" void kernel_launch(void* const* d_in, const int* in_sizes, int n_in,
                              void* d_out, int out_size, void* d_ws, size_t ws_size,
                              hipStream_t stream) {
  const float* x      = (const float*)d_in[0];
  const float* conv_w = (const float*)d_in[1];
  const float* conv_b = (const float*)d_in[2];
  const float* tP[16];
  const float* sP[16];
  for (int i = 0; i < 16; ++i) tP[i] = (const float*)d_in[3 + i];
  for (int i = 0; i < 16; ++i) sP[i] = (const float*)d_in[19 + i];
  const float* gate_w = (const float*)d_in[35];
  const float* gate_b = (const float*)d_in[36];
  const float* proj_w = (const float*)d_in[37];
  const float* proj_b = (const float*)d_in[38];
  float* out = (float*)d_out;

  // ---- workspace (floats): total 27,646,480 f = 110.6 MB
  float* ws    = (float*)d_ws;
  float* x32   = ws;                               // 8,257,536 (2 towers x NT x D)
  unsigned short* wb = (unsigned short*)(x32 + 8257536);  // 5,201,920 shorts
  float* meanb = x32 + 8257536 + 2600960;          // 5,376
  float* stdb  = meanb + 5376;                     // 5,376
  float* R1    = stdb + 5376 + 16;                 // 8,388,608
  float* R2    = R1 + 8388608;                     // 8,388,608

  unsigned short* im2colB = (unsigned short*)R1;             // pre-loop
  unsigned short* Zcat    = (unsigned short*)R1;             // dft -> H1
  unsigned short* Ycat1   = (unsigned short*)(R1 + 4194304); // H1 -> H2
  unsigned short* ptb     = (unsigned short*)(R1 + 4194304); // irfft -> Gp
  unsigned short* gp      = (unsigned short*)R1;             // Gp -> TwLN
  unsigned short* featbf  = (unsigned short*)R1;             // post-loop

  unsigned short* Ycat2b = (unsigned short*)R2;    // H2 -> irfft (bf16 packed)
  unsigned short* hidB = (unsigned short*)R2;      // Ge -> Gp
  float* part   = R2;                              // proj partials (16 x 516096 = 8.26M f)

  unsigned short* convW = wb;                      // 256*352
  unsigned short* sets  = wb + 90112;              // 6 * (Gew 131072 + Gpw 131072 + Tw 65536)
  unsigned short* catW  = wb + 90112 + 1966080;    // 12 * 262144

  // ---- weight prep
  CvtArgs ca; int blk0 = 0, ne = 0;
  auto add_ent = [&](const float* s, unsigned short* d, int rows, int scol, int dcol) {
    ca.e[ne].src = s; ca.e[ne].dst = d; ca.e[ne].rows = rows;
    ca.e[ne].scol = scol; ca.e[ne].dcol = dcol; ca.e[ne].blk0 = blk0;
    blk0 += (rows * dcol + 255) / 256; ++ne;
  };
  add_ent(conv_w, convW, 256, 336, 352);
  for (int tw = 0; tw < 2; ++tw) {
    const float** Pp = tw ? (const float**)sP : (const float**)tP;
    for (int l = 0; l < 3; ++l) {
      unsigned short* sb = sets + (size_t)(tw * 3 + l) * 327680;
      add_ent(Pp[2] + (size_t)l * 131072, sb,          512, 256, 256);  // Gew
      add_ent(Pp[4] + (size_t)l * 131072, sb + 131072, 256, 512, 512);  // Gpw
      add_ent(Pp[0] + (size_t)l * 65536,  sb + 262144, 256, 256, 256);  // Tw
    }
  }
  ca.nent = ne;
  wprep_kernel<<<blk0, 256, 0, stream>>>(ca);

  CatArgs cat;
  for (int tw = 0; tw < 2; ++tw) {
    const float** Pp = tw ? (const float**)sP : (const float**)tP;
    for (int l = 0; l < 3; ++l) {
      int e0 = (tw * 3 + l) * 2;
      cat.wr[e0]     = Pp[6]  + (size_t)l * 65536;   // H1Wr
      cat.wi[e0]     = Pp[7]  + (size_t)l * 65536;   // H1Wi
      cat.wr[e0 + 1] = Pp[10] + (size_t)l * 65536;   // H2Wr
      cat.wi[e0 + 1] = Pp[11] + (size_t)l * 65536;   // H2Wi
    }
  }
  wcat_kernel<<<12 * 1024, 256, 0, stream>>>(cat, catW);

  // ---- stem (norm scatters directly into im2col layout; conv adds PE,
  // writes t-tower only -- layer-0 consumers share via asub/ressub)
  norm_kernel<<<B_ * M_, 256, 0, stream>>>(x, im2colB, meanb, stdb);
  mm_kernel<0, 0, 0, 11, 0, 0, 0, 0, 0, 32, 2, 1><<<dim3(2, 252), 256, 0, stream>>>(
      im2colB, convW, convW, nullptr, conv_b, conv_b, nullptr, x32,
      KCP_, 256, 0, 1 << 30, 0, 0, 0);

  // ---- layers (both towers batched; freq branch first, then MLP with x pt fuse)
  for (int l = 0; l < 3; ++l) {
    unsigned short* st0 = sets + (size_t)l * 327680;
    unsigned short* st1 = sets + (size_t)(3 + l) * 327680;
    unsigned short* c1t0 = catW + (size_t)((0 + l) * 2) * 262144;
    unsigned short* c2t0 = c1t0 + 262144;
    unsigned short* c1t1 = catW + (size_t)((3 + l) * 2) * 262144;
    unsigned short* c2t1 = c1t1 + 262144;
    const int aH1 = (l == 0) ? 8192 * 512 : 0;     // Zcat tower-s -> t rows
    const int aGe = (l == 0) ? NT_ * D_ : 0;       // x32 tower-s -> t rows

    dft_kernel<<<(l == 0 ? B_ : 2 * B_), 256, 0, stream>>>(x32, Zcat);
    mm_kernel<0, 1, 1, 8, 0, 0, 1, 0, 0, 64, 2, 0><<<dim3(4, 256), 256, 0, stream>>>(
        Zcat, c1t0, c1t1, nullptr, tP[9] + (size_t)l * D_, sP[9] + (size_t)l * D_,
        nullptr, Ycat1, 512, 512, 0, 128, 0, 0, aH1);
    mm_kernel<0, 1, 1, 8, 0, 0, 0, 0, 0, 64, 2, 0><<<dim3(4, 256), 256, 0, stream>>>(
        Ycat1, c2t0, c2t1, nullptr, tP[13] + (size_t)l * D_, sP[13] + (size_t)l * D_,
        nullptr, Ycat2b, 512, 512, 0, 128, 0, 0, 0);
    irfft_kernel<<<2 * B_, 256, 0, stream>>>(Ycat2b, ptb);
    mm_kernel<1, 1, 0, 4, 1, 0, 0, 0, 0, 64, 2, 0><<<dim3(4, 504), 256, 0, stream>>>(
        x32, st0, st1, nullptr, tP[3] + (size_t)l * HID_, sP[3] + (size_t)l * HID_,
        nullptr, hidB, 256, 512, 0, 252, 0, 0, aGe);
    mm_kernel<0, 1, 0, 8, 0, 0, 0, 1, 0, 64, 2, 0><<<dim3(2, 504), 256, 0, stream>>>(
        hidB, st0 + 131072, st1 + 131072, nullptr,
        tP[5] + (size_t)l * D_, sP[5] + (size_t)l * D_, ptb, gp, 512, 256, 0, 252, 0, 0, 0);
    twln_kernel<<<504, 256, 0, stream>>>(
        gp, st0 + 262144, st1 + 262144,
        tP[1] + (size_t)l * D_, sP[1] + (size_t)l * D_,
        tP[14] + (size_t)l * D_, tP[15] + (size_t)l * D_,
        sP[14] + (size_t)l * D_, sP[15] + (size_t)l * D_, x32,
        (l == 0) ? NT_ * D_ : 0);
  }

  // ---- head
  gate_feat_kernel<<<NT_ / 4, 256, 0, stream>>>(x32, gate_w, gate_b, featbf);
  // proj: BK=64, A async bf16 + W fp32 reg-staged, PZ=16 z-blocks of 16
  // k64-steps (last z takes 12; totk=252 in BK units). R2 known-best config.
  mm_kernel<0, 0, 2, 0, 0, 1, 0, 0, 1, 64, 2, 0><<<dim3(16, 4, PZ_), 256, 0, stream>>>(
      featbf, nullptr, nullptr, proj_w, nullptr, nullptr, nullptr, part,
      NT_, 2016, 16, 1 << 30, 256, 252, 0);
  final_kernel<<<2016, 256, 0, stream>>>(part, proj_b, stdb, meanb, out);
}